// Round 6
// baseline (272.403 us; speedup 1.0000x reference)
//
#include <hip/hip_runtime.h>

// DSSIM loss, B=32 C=3 H=W=512 fp32, 6x6 gaussian (sigma=1.5), VALID conv.
// R6 = R5 (2 cols/thread, float2 loads, (u,v) 4-quantity form, compile-time
// window rotation) with the OOB fix: load base clamped to ec0=min(c0,506),
// e3=min(ec0+6,510) so every row read stays within elements 0..511 of its row
// (R5 faulted reading past the tensor end on the last row for tid>=254, whose
// columns are masked anyway). Inputs uniform [0,1) -> L=1 -> C1=1e-4, C2=9e-4.

#define HW      512
#define OUT_HW  507
#define PLANES  96
#define NCHUNK  16           // 15 chunks x 32 output rows + 1 x 27

// normalized gaussian taps [g0,g1,g2,g3,g2,g1]
static constexpr double G0_ = 0.13533528323661270;   // exp(-2)
static constexpr double G1_ = 0.41111229050718745;   // exp(-8/9)
static constexpr double G2_ = 0.80073740291680810;   // exp(-2/9)
static constexpr double GS_ = G0_ + G1_ + G2_ + 1.0 + G2_ + G1_;
#define GW0 ((float)(G0_/GS_))
#define GW1 ((float)(G1_/GS_))
#define GW2 ((float)(G2_/GS_))
#define GW3 ((float)(1.0/GS_))
#define C1x2 2.0e-4f         // 2*C1
#define C2x2 1.8e-3f         // 2*C2

// ---- load row (8 elements via 4 float2 per input), prep once per element,
// ---- h-filter 2 cols x 4 quantities into window slot S (compile-time) ----
#define ROW(S)                                                                  \
    {                                                                           \
        const float2 xq0 = *(const float2*)(X + i);                             \
        const float2 xq1 = *(const float2*)(X + i + 2);                         \
        const float2 xq2 = *(const float2*)(X + i + 4);                         \
        const float2 xq3 = *(const float2*)(X + i3);                            \
        const float2 yq0 = *(const float2*)(Y + i);                             \
        const float2 yq1 = *(const float2*)(Y + i + 2);                         \
        const float2 yq2 = *(const float2*)(Y + i + 4);                         \
        const float2 yq3 = *(const float2*)(Y + i3);                            \
        i += HW; i3 += HW;                                                      \
        const float u0 = xq0.x + yq0.x, v0 = xq0.x - yq0.x;                     \
        const float u1 = xq0.y + yq0.y, v1 = xq0.y - yq0.y;                     \
        const float u2 = xq1.x + yq1.x, v2 = xq1.x - yq1.x;                     \
        const float u3 = xq1.y + yq1.y, v3 = xq1.y - yq1.y;                     \
        const float u4 = xq2.x + yq2.x, v4 = xq2.x - yq2.x;                     \
        const float u5 = xq2.y + yq2.y, v5 = xq2.y - yq2.y;                     \
        const float u6 = xq3.x + yq3.x, v6 = xq3.x - yq3.x;                     \
        const float uu0 = u0*u0, uu1 = u1*u1, uu2 = u2*u2, uu3 = u3*u3;         \
        const float uu4 = u4*u4, uu5 = u5*u5, uu6 = u6*u6;                      \
        const float vv0 = v0*v0, vv1 = v1*v1, vv2 = v2*v2, vv3 = v3*v3;         \
        const float vv4 = v4*v4, vv5 = v5*v5, vv6 = v6*v6;                      \
        wuA[S]  = GW0*u0  + GW1*u1  + GW2*u2  + GW3*u3  + GW2*u4  + GW1*u5;     \
        wuB[S]  = GW0*u1  + GW1*u2  + GW2*u3  + GW3*u4  + GW2*u5  + GW1*u6;     \
        wvA[S]  = GW0*v0  + GW1*v1  + GW2*v2  + GW3*v3  + GW2*v4  + GW1*v5;     \
        wvB[S]  = GW0*v1  + GW1*v2  + GW2*v3  + GW3*v4  + GW2*v5  + GW1*v6;     \
        wuuA[S] = GW0*uu0 + GW1*uu1 + GW2*uu2 + GW3*uu3 + GW2*uu4 + GW1*uu5;    \
        wuuB[S] = GW0*uu1 + GW1*uu2 + GW2*uu3 + GW3*uu4 + GW2*uu5 + GW1*uu6;    \
        wvvA[S] = GW0*vv0 + GW1*vv1 + GW2*vv2 + GW3*vv3 + GW2*vv4 + GW1*vv5;    \
        wvvB[S] = GW0*vv1 + GW1*vv2 + GW2*vv3 + GW3*vv4 + GW2*vv5 + GW1*vv6;    \
    }

// ---- vertical filter + SSIM for both cols; newest slot is S ----
#define OUTP(S)                                                                 \
    {                                                                           \
        float VuA = 0.f, VvA = 0.f, VuuA = 0.f, VvvA = 0.f;                     \
        float VuB = 0.f, VvB = 0.f, VuuB = 0.f, VvvB = 0.f;                     \
        _Pragma("unroll") for (int d = 0; d < 6; ++d) {                         \
            const int s = ((S) + 1 + d) % 6;                                    \
            const float g = gw[d];                                              \
            VuA  += g * wuA[s];   VuB  += g * wuB[s];                           \
            VvA  += g * wvA[s];   VvB  += g * wvB[s];                           \
            VuuA += g * wuuA[s];  VuuB += g * wuuB[s];                          \
            VvvA += g * wvvA[s];  VvvB += g * wvvB[s];                          \
        }                                                                       \
        {                                                                       \
            const float A  = VuA * VuA, B = VvA * VvA;                          \
            const float P  = A - B, Q = A + B;                                  \
            const float R  = (VuuA - VvvA) - P;                                 \
            const float Sg = (VuuA + VvvA) - Q;                                 \
            const float num = (P + C1x2) * (R + C2x2);                          \
            const float den = (Q + C1x2) * (Sg + C2x2);                         \
            sum += mA * (num * __builtin_amdgcn_rcpf(den));                     \
        }                                                                       \
        {                                                                       \
            const float A  = VuB * VuB, B = VvB * VvB;                          \
            const float P  = A - B, Q = A + B;                                  \
            const float R  = (VuuB - VvvB) - P;                                 \
            const float Sg = (VuuB + VvvB) - Q;                                 \
            const float num = (P + C1x2) * (R + C2x2);                          \
            const float den = (Q + C1x2) * (Sg + C2x2);                         \
            sum += mB * (num * __builtin_amdgcn_rcpf(den));                     \
        }                                                                       \
    }

template <int NOUT>
__device__ __forceinline__ float run_block(const float* __restrict__ X,
                                           const float* __restrict__ Y,
                                           unsigned i, unsigned i3,
                                           float mA, float mB) {
    const float gw[6] = {GW0, GW1, GW2, GW3, GW2, GW1};
    float wuA[6], wuB[6], wvA[6], wvB[6];
    float wuuA[6], wuuB[6], wvvA[6], wvvB[6];
    float sum = 0.f;

    // prologue: rows 0..4 -> slots 0..4; row 5 -> slot 5 + first output row
    ROW(0) ROW(1) ROW(2) ROW(3) ROW(4)
    ROW(5) OUTP(5)

    constexpr int REM  = NOUT - 1;
    constexpr int FULL = REM / 6;
    constexpr int TAIL = REM % 6;

    for (int g6 = 0; g6 < FULL; ++g6) {
        ROW(0) OUTP(0) ROW(1) OUTP(1) ROW(2) OUTP(2)
        ROW(3) OUTP(3) ROW(4) OUTP(4) ROW(5) OUTP(5)
    }
    if constexpr (TAIL > 0) { ROW(0) OUTP(0) }
    if constexpr (TAIL > 1) { ROW(1) OUTP(1) }
    if constexpr (TAIL > 2) { ROW(2) OUTP(2) }
    if constexpr (TAIL > 3) { ROW(3) OUTP(3) }
    if constexpr (TAIL > 4) { ROW(4) OUTP(4) }

    return sum;
}

#undef ROW
#undef OUTP

__global__ __launch_bounds__(256) void dssim_main(const float* __restrict__ X,
                                                  const float* __restrict__ Y,
                                                  double* __restrict__ acc) {
    const int tid   = threadIdx.x;
    const int c0    = 2 * tid;                       // cols c0, c0+1
    const int chunk = blockIdx.x;
    const int plane = blockIdx.y;
    const int row0  = chunk * 32;

    const float mA = (c0     < OUT_HW) ? 1.f : 0.f;
    const float mB = (c0 + 1 < OUT_HW) ? 1.f : 0.f;

    // Clamp load base so row reads span elements ec0..ec0+7 <= 511 (in-row,
    // never OOB). Only tid>=254 shifts (both its cols are masked); tid=253's
    // valid col 506 still reads its exact taps 506..511.
    const int ec0 = (c0 < 506) ? c0 : 506;
    const int e3  = (ec0 + 6 < 510) ? (ec0 + 6) : 510;  // 4th float2, clamped

    const unsigned base = (unsigned)plane * (HW * HW) + (unsigned)row0 * HW;
    const unsigned i  = base + (unsigned)ec0;
    const unsigned i3 = base + (unsigned)e3;

    float sum;
    if (chunk == NCHUNK - 1) sum = run_block<27>(X, Y, i, i3, mA, mB);
    else                     sum = run_block<32>(X, Y, i, i3, mA, mB);

    // reduction: wave shfl -> LDS across 4 waves -> one f64 atomic per block
#pragma unroll
    for (int off = 32; off > 0; off >>= 1)
        sum += __shfl_down(sum, off, 64);

    __shared__ float wsum[4];
    const int wave = tid >> 6;
    const int lane = tid & 63;
    if (lane == 0) wsum[wave] = sum;
    __syncthreads();
    if (tid == 0) {
        double b = (double)wsum[0] + (double)wsum[1] + (double)wsum[2] + (double)wsum[3];
        atomicAdd(acc, b);
    }
}

__global__ void dssim_final(const double* __restrict__ acc, float* __restrict__ out) {
    const double n    = (double)PLANES * (double)OUT_HW * (double)OUT_HW;
    const double mean = acc[0] / n;
    out[0] = (float)((1.0 - mean) * 0.5);
}

extern "C" void kernel_launch(void* const* d_in, const int* in_sizes, int n_in,
                              void* d_out, int out_size, void* d_ws, size_t ws_size,
                              hipStream_t stream) {
    const float* x = (const float*)d_in[0];
    const float* y = (const float*)d_in[1];
    float* out  = (float*)d_out;
    double* acc = (double*)d_ws;

    hipMemsetAsync(acc, 0, sizeof(double), stream);

    dim3 grid(NCHUNK, PLANES);   // 16 x 96 = 1536 blocks, 6144 waves
    dssim_main<<<grid, 256, 0, stream>>>(x, y, acc);
    dssim_final<<<1, 1, 0, stream>>>(acc, out);
}